// Round 13
// baseline (42.014 us; speedup 1.0000x reference)
//
#include <hip/hip_runtime.h>
#include <math.h>

// Problem constants (fixed by setup_inputs)
constexpr int N    = 4;
constexpr int C    = 16;
constexpr int Hin  = 288;
constexpr int Win  = 1216;
constexpr int Hout = 800;
constexpr int Wout = 400;
constexpr int PIX_PER_N = Hout * Wout;       // 320000
constexpr int CH_STRIDE = Hin * Win;         // 350208
constexpr int NBLK = (N * Hout * Wout) / 256; // 5000 blocks (exact)
constexpr int NXCD = 8;
constexpr int BLK_PER_XCD = NBLK / NXCD;     // 625 (5000 % 8 == 0: bijective)

// Base-grid constants (exact reference f32 values; see round-6 derivation).
constexpr double grd = 0.05 * (800.0 / (double)Hout);        // 0.05 (f64)
constexpr float  GR  = (float)grd;                            // f32(0.05)
constexpr float  CX0 = (float)(-10.0 + grd / 2.0);            // f32(-9.975)
constexpr float  CY0 = (float)( 46.0 - grd / 2.0);            // f32(45.975)

// Register barrier: keeps ops separately rounded exactly where the numpy
// reference's ufuncs are separately rounded (correctness-critical near the
// g2~0 projective singularity). Coordinate chain ONLY.
__device__ __forceinline__ float fbar(float x) {
    asm volatile("" : "+v"(x));
    return x;
}

__global__ __launch_bounds__(256) void bev_sample_kernel(
    const float* __restrict__ x,      // (N, C, Hin, Win)
    const float* __restrict__ theta,  // (N, 3, 3)
    const float* __restrict__ shift,  // (N,)
    float* __restrict__ out)          // (N, C, Hout, Wout)
{
    // XCD-aware swizzle: hardware round-robins blockIdx across the 8 XCDs
    // (xcd = bid % 8). Remap so each XCD processes a CONTIGUOUS run of 625
    // blocks (~100 consecutive output rows -> ~3 MB of consecutive input
    // rows), converting gather L3-hits (~500 cy) into L2-hits (~200 cy).
    // 5000 % 8 == 0 so this permutation is bijective.
    int bid = (int)blockIdx.x;
    int sbid = (bid % NXCD) * BLK_PER_XCD + bid / NXCD;

    int idx = sbid * 256 + threadIdx.x;

    int w = idx % Wout;
    int t = idx / Wout;
    int h = t % Hout;
    int n = t / Hout;

    // ---- coordinate chain: bit-exact vs harness np reference (round 6) ----
    float bx = CX0 + fbar(GR * (float)w);
    float by = CY0 - fbar(GR * (float)h);

    const float* th = theta + n * 9;
    float t00 = th[0], t01 = th[1], t02 = th[2];
    float t10 = th[3], t11 = th[4], t12 = th[5];
    float t20 = th[6], t21 = th[7], t22 = th[8];

    // Einsum flavor F: ascending-k FMA accumulation (matches the reference).
    float g0 = fbar(__builtin_fmaf(by, t01, fbar(bx * t00))) + t02;
    float g1 = fbar(__builtin_fmaf(by, t11, fbar(bx * t10))) + t12;
    float g2 = fbar(__builtin_fmaf(by, t21, fbar(bx * t20))) + t22;

    float p0 = g0 / g2;
    float p1 = g1 / g2;

    float gx = fbar(p0 / 608.0f) - 1.0f;
    float gy = fbar((p1 - shift[n]) / 144.0f) - 1.0f;

    float ix = (fbar((gx + 1.0f) * (float)Win) - 1.0f) * 0.5f;
    float iy = (fbar((gy + 1.0f) * (float)Hin) - 1.0f) * 0.5f;

    float ix0f = floorf(ix);
    float iy0f = floorf(iy);
    float wx = ix - ix0f;
    float wy = iy - iy0f;

    int x0 = (int)fminf(fmaxf(ix0f,        0.0f), (float)(Win - 1));
    int x1 = (int)fminf(fmaxf(ix0f + 1.0f, 0.0f), (float)(Win - 1));
    int y0 = (int)fminf(fmaxf(iy0f,        0.0f), (float)(Hin - 1));
    int y1 = (int)fminf(fmaxf(iy0f + 1.0f, 0.0f), (float)(Hin - 1));

    float omwx = 1.0f - wx;
    float omwy = 1.0f - wy;
    float w00 = omwx * omwy;
    float w01 = wx * omwy;
    float w10 = omwx * wy;
    float w11 = wx * wy;

    // ---- horizontal corner pairing: one dwordx2 load covers (x0, x1) ----
    int lo0 = y0 * Win + x0;
    int lo1 = y1 * Win + x0;
    int lb0 = min(lo0, CH_STRIDE - 2);
    int lb1 = min(lo1, CH_STRIDE - 2);
    bool hi0   = lo0 > lb0;
    bool hi1   = lo1 > lb1;
    bool xpair = x1 > x0;

    const float* xb = x + (size_t)n * C * CH_STRIDE;

    // Phase 1: 32 independent dwordx2 gathers in flight.
    float2 r0[C], r1[C];
    #pragma unroll
    for (int c = 0; c < C; ++c) {
        const float* pch = xb + (size_t)c * CH_STRIDE;
        r0[c] = *reinterpret_cast<const float2*>(pch + lb0);
        r1[c] = *reinterpret_cast<const float2*>(pch + lb1);
    }

    // Phase 2: select corners, combine, streaming stores.
    size_t obase = ((size_t)(n * C) * Hout + h) * Wout + w;
    #pragma unroll
    for (int c = 0; c < C; ++c) {
        float v00 = hi0   ? r0[c].y : r0[c].x;
        float v01 = xpair ? r0[c].y : v00;
        float v10 = hi1   ? r1[c].y : r1[c].x;
        float v11 = xpair ? r1[c].y : v10;
        float r = v00 * w00 + v01 * w01 + v10 * w10 + v11 * w11;
        __builtin_nontemporal_store(r, &out[obase + (size_t)c * PIX_PER_N]);
    }
}

extern "C" void kernel_launch(void* const* d_in, const int* in_sizes, int n_in,
                              void* d_out, int out_size, void* d_ws, size_t ws_size,
                              hipStream_t stream) {
    const float* x     = (const float*)d_in[0];
    const float* theta = (const float*)d_in[1];
    const float* shift = (const float*)d_in[2];
    float* out = (float*)d_out;

    bev_sample_kernel<<<NBLK, 256, 0, stream>>>(x, theta, shift, out);
}

// Round 14
// 39.103 us; speedup vs baseline: 1.0744x; 1.0744x over previous
//
#include <hip/hip_runtime.h>
#include <math.h>

// Problem constants (fixed by setup_inputs)
constexpr int N    = 4;
constexpr int C    = 16;
constexpr int Hin  = 288;
constexpr int Win  = 1216;
constexpr int Hout = 800;
constexpr int Wout = 400;
constexpr int PIX_PER_N = Hout * Wout;       // 320000
constexpr int CH_STRIDE = Hin * Win;         // 350208

// Base-grid constants (exact reference f32 values; see round-6 derivation).
constexpr double grd = 0.05 * (800.0 / (double)Hout);        // 0.05 (f64)
constexpr float  GR  = (float)grd;                            // f32(0.05)
constexpr float  CX0 = (float)(-10.0 + grd / 2.0);            // f32(-9.975)
constexpr float  CY0 = (float)( 46.0 - grd / 2.0);            // f32(45.975)

// Register barrier: keeps ops separately rounded exactly where the numpy
// reference's ufuncs are separately rounded (correctness-critical near the
// g2~0 projective singularity). Coordinate chain ONLY.
__device__ __forceinline__ float fbar(float x) {
    asm volatile("" : "+v"(x));
    return x;
}

__global__ __launch_bounds__(256) void bev_sample_kernel(
    const float* __restrict__ x,      // (N, C, Hin, Win)
    const float* __restrict__ theta,  // (N, 3, 3)
    const float* __restrict__ shift,  // (N,)
    float* __restrict__ out)          // (N, C, Hout, Wout)
{
    // R10 body exactly; single A/B variable this round: NT stores -> plain
    // stores (L2 write-allocate absorbs the 80 MB stream and drains
    // asynchronously, decoupling wave retirement from HBM write latency).
    int idx = blockIdx.x * 256 + threadIdx.x;
    if (idx >= N * Hout * Wout) return;

    int w = idx % Wout;
    int t = idx / Wout;
    int h = t % Hout;
    int n = t / Hout;

    // ---- coordinate chain: bit-exact vs harness np reference (round 6) ----
    float bx = CX0 + fbar(GR * (float)w);
    float by = CY0 - fbar(GR * (float)h);

    const float* th = theta + n * 9;
    float t00 = th[0], t01 = th[1], t02 = th[2];
    float t10 = th[3], t11 = th[4], t12 = th[5];
    float t20 = th[6], t21 = th[7], t22 = th[8];

    // Einsum flavor F: ascending-k FMA accumulation (matches the reference).
    float g0 = fbar(__builtin_fmaf(by, t01, fbar(bx * t00))) + t02;
    float g1 = fbar(__builtin_fmaf(by, t11, fbar(bx * t10))) + t12;
    float g2 = fbar(__builtin_fmaf(by, t21, fbar(bx * t20))) + t22;

    float p0 = g0 / g2;
    float p1 = g1 / g2;

    float gx = fbar(p0 / 608.0f) - 1.0f;
    float gy = fbar((p1 - shift[n]) / 144.0f) - 1.0f;

    float ix = (fbar((gx + 1.0f) * (float)Win) - 1.0f) * 0.5f;
    float iy = (fbar((gy + 1.0f) * (float)Hin) - 1.0f) * 0.5f;

    float ix0f = floorf(ix);
    float iy0f = floorf(iy);
    float wx = ix - ix0f;
    float wy = iy - iy0f;

    int x0 = (int)fminf(fmaxf(ix0f,        0.0f), (float)(Win - 1));
    int x1 = (int)fminf(fmaxf(ix0f + 1.0f, 0.0f), (float)(Win - 1));
    int y0 = (int)fminf(fmaxf(iy0f,        0.0f), (float)(Hin - 1));
    int y1 = (int)fminf(fmaxf(iy0f + 1.0f, 0.0f), (float)(Hin - 1));

    float omwx = 1.0f - wx;
    float omwy = 1.0f - wy;
    float w00 = omwx * omwy;
    float w01 = wx * omwy;
    float w10 = omwx * wy;
    float w11 = wx * wy;

    // ---- horizontal corner pairing: one dwordx2 load covers (x0, x1) ----
    int lo0 = y0 * Win + x0;
    int lo1 = y1 * Win + x0;
    int lb0 = min(lo0, CH_STRIDE - 2);
    int lb1 = min(lo1, CH_STRIDE - 2);
    bool hi0   = lo0 > lb0;
    bool hi1   = lo1 > lb1;
    bool xpair = x1 > x0;

    const float* xb = x + (size_t)n * C * CH_STRIDE;

    // Phase 1: 32 independent dwordx2 gathers in flight.
    float2 r0[C], r1[C];
    #pragma unroll
    for (int c = 0; c < C; ++c) {
        const float* pch = xb + (size_t)c * CH_STRIDE;
        r0[c] = *reinterpret_cast<const float2*>(pch + lb0);
        r1[c] = *reinterpret_cast<const float2*>(pch + lb1);
    }

    // Phase 2: select corners, combine, plain coalesced stores.
    size_t obase = ((size_t)(n * C) * Hout + h) * Wout + w;
    #pragma unroll
    for (int c = 0; c < C; ++c) {
        float v00 = hi0   ? r0[c].y : r0[c].x;
        float v01 = xpair ? r0[c].y : v00;
        float v10 = hi1   ? r1[c].y : r1[c].x;
        float v11 = xpair ? r1[c].y : v10;
        float r = v00 * w00 + v01 * w01 + v10 * w10 + v11 * w11;
        out[obase + (size_t)c * PIX_PER_N] = r;
    }
}

extern "C" void kernel_launch(void* const* d_in, const int* in_sizes, int n_in,
                              void* d_out, int out_size, void* d_ws, size_t ws_size,
                              hipStream_t stream) {
    const float* x     = (const float*)d_in[0];
    const float* theta = (const float*)d_in[1];
    const float* shift = (const float*)d_in[2];
    float* out = (float*)d_out;

    int total = N * Hout * Wout;  // 1,280,000 pixel threads = 5000 blocks
    int blocks = (total + 255) / 256;
    bev_sample_kernel<<<blocks, 256, 0, stream>>>(x, theta, shift, out);
}

// Round 15
// 36.817 us; speedup vs baseline: 1.1412x; 1.0621x over previous
//
#include <hip/hip_runtime.h>
#include <math.h>

// Problem constants (fixed by setup_inputs)
constexpr int N    = 4;
constexpr int C    = 16;
constexpr int Hin  = 288;
constexpr int Win  = 1216;
constexpr int Hout = 800;
constexpr int Wout = 400;
constexpr int PIX_PER_N = Hout * Wout;       // 320000
constexpr int CH_STRIDE = Hin * Win;         // 350208
constexpr int TOTAL = N * Hout * Wout;       // 1,280,000
constexpr int HALF  = TOTAL / 2;             // 640,000

// Base-grid constants (exact reference f32 values; see round-6 derivation).
constexpr double grd = 0.05 * (800.0 / (double)Hout);        // 0.05 (f64)
constexpr float  GR  = (float)grd;                            // f32(0.05)
constexpr float  CX0 = (float)(-10.0 + grd / 2.0);            // f32(-9.975)
constexpr float  CY0 = (float)( 46.0 - grd / 2.0);            // f32(45.975)

// Register barrier: keeps ops separately rounded exactly where the numpy
// reference's ufuncs are separately rounded (correctness-critical near the
// g2~0 projective singularity). Coordinate chain ONLY.
__device__ __forceinline__ float fbar(float x) {
    asm volatile("" : "+v"(x));
    return x;
}

struct Samp {
    int   lb0, lb1;           // clamped dwordx2 load bases (row y0 / y1)
    bool  hi0, hi1, xpair;    // corner-select flags
    float w00, w01, w10, w11; // bilinear weights
};

// Bit-exact coordinate chain (verified round 6: flavor-F einsum, IEEE divs,
// separately-rounded ufunc chain). DO NOT TOUCH.
__device__ __forceinline__ Samp px_chain(int w, int h, const float* th, float shn) {
    float bx = CX0 + fbar(GR * (float)w);
    float by = CY0 - fbar(GR * (float)h);

    float t00 = th[0], t01 = th[1], t02 = th[2];
    float t10 = th[3], t11 = th[4], t12 = th[5];
    float t20 = th[6], t21 = th[7], t22 = th[8];

    float g0 = fbar(__builtin_fmaf(by, t01, fbar(bx * t00))) + t02;
    float g1 = fbar(__builtin_fmaf(by, t11, fbar(bx * t10))) + t12;
    float g2 = fbar(__builtin_fmaf(by, t21, fbar(bx * t20))) + t22;

    float p0 = g0 / g2;
    float p1 = g1 / g2;

    float gx = fbar(p0 / 608.0f) - 1.0f;
    float gy = fbar((p1 - shn) / 144.0f) - 1.0f;

    float ix = (fbar((gx + 1.0f) * (float)Win) - 1.0f) * 0.5f;
    float iy = (fbar((gy + 1.0f) * (float)Hin) - 1.0f) * 0.5f;

    float ix0f = floorf(ix);
    float iy0f = floorf(iy);
    float wx = ix - ix0f;
    float wy = iy - iy0f;

    int x0 = (int)fminf(fmaxf(ix0f,        0.0f), (float)(Win - 1));
    int x1 = (int)fminf(fmaxf(ix0f + 1.0f, 0.0f), (float)(Win - 1));
    int y0 = (int)fminf(fmaxf(iy0f,        0.0f), (float)(Hin - 1));
    int y1 = (int)fminf(fmaxf(iy0f + 1.0f, 0.0f), (float)(Hin - 1));

    float omwx = 1.0f - wx;
    float omwy = 1.0f - wy;

    Samp s;
    s.w00 = omwx * omwy;
    s.w01 = wx * omwy;
    s.w10 = omwx * wy;
    s.w11 = wx * wy;

    int lo0 = y0 * Win + x0;
    int lo1 = y1 * Win + x0;
    s.lb0 = min(lo0, CH_STRIDE - 2);
    s.lb1 = min(lo1, CH_STRIDE - 2);
    s.hi0 = lo0 > s.lb0;
    s.hi1 = lo1 > s.lb1;
    s.xpair = x1 > x0;
    return s;
}

__device__ __forceinline__ float combine(float2 r0, float2 r1, const Samp& s) {
    float v00 = s.hi0   ? r0.y : r0.x;
    float v01 = s.xpair ? r0.y : v00;
    float v10 = s.hi1   ? r1.y : r1.x;
    float v11 = s.xpair ? r1.y : v10;
    return v00 * s.w00 + v01 * s.w01 + v10 * s.w10 + v11 * s.w11;
}

__global__ __launch_bounds__(256) void bev_sample_kernel(
    const float* __restrict__ x,      // (N, C, Hin, Win)
    const float* __restrict__ theta,  // (N, 3, 3)
    const float* __restrict__ shift,  // (N,)
    float* __restrict__ out)          // (N, C, Hout, Wout)
{
    // Software-pipelined 2 pixels/thread (pid, pid+HALF):
    //   chainA -> issue 32 A-gathers -> chainB (hides A latency) ->
    //   issue 32 B-gathers -> combine/store A (vmcnt waits A only) ->
    //   combine/store B.
    // 64 loads in flight, no mid-batch drain (R12's failure mode).
    int gid = blockIdx.x * 256 + threadIdx.x;   // 0..HALF-1 (2500 blocks)

    // ---------------- pixel A ----------------
    int wA = gid % Wout;
    int tA = gid / Wout;
    int hA = tA % Hout;
    int nA = tA / Hout;                          // block-uniform (1250 blk/n)
    int nAs = __builtin_amdgcn_readfirstlane(nA);

    Samp sA = px_chain(wA, hA, theta + nAs * 9, shift[nAs]);
    const float* xbA = x + (size_t)nAs * C * CH_STRIDE;

    float2 rA0[C], rA1[C];
    #pragma unroll
    for (int c = 0; c < C; ++c) {
        const float* p = xbA + (size_t)c * CH_STRIDE;
        rA0[c] = *reinterpret_cast<const float2*>(p + sA.lb0);
        rA1[c] = *reinterpret_cast<const float2*>(p + sA.lb1);
    }

    // ---------------- pixel B (chain overlaps A's loads) ----------------
    int pidB = gid + HALF;
    int wB = pidB % Wout;
    int tB = pidB / Wout;
    int hB = tB % Hout;
    int nB = tB / Hout;
    int nBs = __builtin_amdgcn_readfirstlane(nB);

    Samp sB = px_chain(wB, hB, theta + nBs * 9, shift[nBs]);
    const float* xbB = x + (size_t)nBs * C * CH_STRIDE;

    float2 rB0[C], rB1[C];
    #pragma unroll
    for (int c = 0; c < C; ++c) {
        const float* p = xbB + (size_t)c * CH_STRIDE;
        rB0[c] = *reinterpret_cast<const float2*>(p + sB.lb0);
        rB1[c] = *reinterpret_cast<const float2*>(p + sB.lb1);
    }

    // ---------------- combine + NT store A ----------------
    size_t obA = ((size_t)(nAs * C) * Hout + hA) * Wout + wA;
    #pragma unroll
    for (int c = 0; c < C; ++c) {
        float r = combine(rA0[c], rA1[c], sA);
        __builtin_nontemporal_store(r, &out[obA + (size_t)c * PIX_PER_N]);
    }

    // ---------------- combine + NT store B ----------------
    size_t obB = ((size_t)(nBs * C) * Hout + hB) * Wout + wB;
    #pragma unroll
    for (int c = 0; c < C; ++c) {
        float r = combine(rB0[c], rB1[c], sB);
        __builtin_nontemporal_store(r, &out[obB + (size_t)c * PIX_PER_N]);
    }
}

extern "C" void kernel_launch(void* const* d_in, const int* in_sizes, int n_in,
                              void* d_out, int out_size, void* d_ws, size_t ws_size,
                              hipStream_t stream) {
    const float* x     = (const float*)d_in[0];
    const float* theta = (const float*)d_in[1];
    const float* shift = (const float*)d_in[2];
    float* out = (float*)d_out;

    int blocks = HALF / 256;                     // 2500, exact
    bev_sample_kernel<<<blocks, 256, 0, stream>>>(x, theta, shift, out);
}